// Round 13
// baseline (226.263 us; speedup 1.0000x reference)
//
#include <hip/hip_runtime.h>
#include <cmath>

// Problem constants
#define B_   8
#define N_   4096
#define DIN1 64
#define DHID 128
#define DOUT2 64
#define MAXDEG 256

typedef float f32x2 __attribute__((ext_vector_type(2)));

// ---------------- bf16 helpers -------------------------------------------
__device__ __forceinline__ unsigned pack2bf(float a, float b) {
    unsigned ua = __float_as_uint(a), ub = __float_as_uint(b);
    ua = (ua + 0x7FFFu + ((ua >> 16) & 1u)) >> 16;
    ub = (ub + 0x7FFFu + ((ub >> 16) & 1u)) & 0xFFFF0000u;
    return ua | ub;          // lo half = a, hi half = b
}
// LAZY unpack into a packed float2: hi element keeps low-16 garbage bits
// (<=2^-7 relative mantissa perturbation, exponent untouched). Deterministic;
// identical for q-init and loop -> self score bit-exact.
__device__ __forceinline__ f32x2 lazy2(unsigned u) {
    f32x2 r;
    r.x = __uint_as_float(u << 16);
    r.y = __uint_as_float(u);
    return r;
}

template <int SH>
__device__ __forceinline__ float dpp_shr_add(float p) {
    int t = __builtin_amdgcn_update_dpp(0, __float_as_int(p),
                                        0x110 | SH, 0xF, 0xF, true);
    return p + __int_as_float(t);
}
// Row-sum lands on the TOP lane of each GRPL-lane subgroup.
template <int GRPL>
__device__ __forceinline__ float dpp_reduce(float p) {
    if constexpr (GRPL == 16) p = dpp_shr_add<8>(p);
    p = dpp_shr_add<4>(p);
    p = dpp_shr_add<2>(p);
    p = dpp_shr_add<1>(p);
    return p;   // valid on lane GRPL-1 of each subgroup
}

// ---------------------------------------------------------------------------
// Kernel 1: adjacency -> neighbor lists. Wave per row, ballot compaction.
// ---------------------------------------------------------------------------
__global__ __launch_bounds__(256) void k_build_csr(
    const float* __restrict__ graph, int* __restrict__ cnt, int* __restrict__ idx)
{
    const int wave = threadIdx.x >> 6;
    const int lane = threadIdx.x & 63;
    const int n = blockIdx.x * 4 + wave;
    const unsigned long long below_mask = (1ULL << lane) - 1ULL;

    const float4* __restrict__ row4 = (const float4*)(graph + (size_t)n * N_);
    int* __restrict__ myidx = idx + (size_t)n * MAXDEG;

    int base = 0;
    for (int it = 0; it < N_ / 256; ++it) {
        const int i4 = it * 64 + lane;
        float4 g = row4[i4];
        const int e = 4 * i4;
#pragma unroll
        for (int c = 0; c < 4; ++c) {
            const float gc = (c == 0) ? g.x : (c == 1) ? g.y : (c == 2) ? g.z : g.w;
            const unsigned long long mk = __ballot(gc != 0.0f);
            const int pos = base + __popcll(mk & below_mask);
            if (gc != 0.0f && pos < MAXDEG) myidx[pos] = e + c;
            base += __popcll(mk);
        }
    }
    if (lane == 0) cnt[n] = (base < MAXDEG) ? base : MAXDEG;
}

// ---------------------------------------------------------------------------
// Kernel 2a: linear1, DUAL WRITE (fp32 + bf16) + LDS-epilogue norms.
// OCCUPANCY RESTRUCTURE (R13): 16 rows/block (grid 2048 -> 8 blocks/CU) and
// K-SPLIT W staging (stage DIN/2 input dims at a time in a half-size LDS
// buffer, barrier, restage) -> LDS 34KB -> 18.6KB -> 32 waves/CU (was 16,
// grid+LDS capped). The d4 loop walks halves in ascending order with the
// identical FMA expression -> h1 bit-identical to R12's.
// ---------------------------------------------------------------------------
__global__ __launch_bounds__(256) void k_linear1(
    const float* __restrict__ x, const float* __restrict__ W,
    float* __restrict__ out, void* __restrict__ outb, float* __restrict__ nrm)
{
    constexpr int DIN = DIN1, DOUT = DHID;   // 64, 128
    constexpr int KT   = DIN / 2;            // 32 dims per stage
    constexpr int CG   = DOUT / 4;           // 32
    constexpr int RG   = 256 / CG;           // 8
    constexpr int ROWS = 16;
    constexpr int TR   = ROWS / RG;          // 2

    __shared__ float sWt[KT][DOUT + 4];      // 16.9 KB
    __shared__ float sL2[ROWS][CG + 1];      // 2.1 KB

    const int t = threadIdx.x;
    const int rg = t / CG;
    const int c  = t % CG;
    const int base = blockIdx.x * ROWS;
    const float4* x4 = (const float4*)x;
    const float4* W4 = (const float4*)W;

    float acc[TR][4];
#pragma unroll
    for (int i = 0; i < TR; ++i)
#pragma unroll
        for (int j = 0; j < 4; ++j) acc[i][j] = 0.0f;

    for (int half = 0; half < 2; ++half) {
        if (half) __syncthreads();           // prev-half reads done
        for (int i = t; i < DOUT * (KT / 4); i += 256) {
            int kk = i / (KT / 4);
            int d4 = i % (KT / 4);
            float4 w = W4[kk * (DIN / 4) + half * (KT / 4) + d4];
            sWt[4 * d4 + 0][kk] = w.x;
            sWt[4 * d4 + 1][kk] = w.y;
            sWt[4 * d4 + 2][kk] = w.z;
            sWt[4 * d4 + 3][kk] = w.w;
        }
        __syncthreads();

        for (int d4 = 0; d4 < KT / 4; ++d4) {
            const int d4g = half * (KT / 4) + d4;
            float4 xf[TR];
#pragma unroll
            for (int i = 0; i < TR; ++i)
                xf[i] = x4[(size_t)(base + rg * TR + i) * (DIN / 4) + d4g];
            float4 wf[4];
#pragma unroll
            for (int dd = 0; dd < 4; ++dd)
                wf[dd] = *(const float4*)&sWt[4 * d4 + dd][4 * c];
#pragma unroll
            for (int i = 0; i < TR; ++i) {
                acc[i][0] += xf[i].x * wf[0].x + xf[i].y * wf[1].x + xf[i].z * wf[2].x + xf[i].w * wf[3].x;
                acc[i][1] += xf[i].x * wf[0].y + xf[i].y * wf[1].y + xf[i].z * wf[2].y + xf[i].w * wf[3].y;
                acc[i][2] += xf[i].x * wf[0].z + xf[i].y * wf[1].z + xf[i].z * wf[2].z + xf[i].w * wf[3].z;
                acc[i][3] += xf[i].x * wf[0].w + xf[i].y * wf[1].w + xf[i].z * wf[2].w + xf[i].w * wf[3].w;
            }
        }
    }

#pragma unroll
    for (int i = 0; i < TR; ++i) {
        const size_t row = (size_t)(base + rg * TR + i);
        float4 o = {acc[i][0], acc[i][1], acc[i][2], acc[i][3]};
        ((float4*)out)[row * CG + c] = o;
        uint2 ob = {pack2bf(o.x, o.y), pack2bf(o.z, o.w)};
        *(uint2*)((char*)outb + row * (DOUT * 2) + c * 8) = ob;
        sL2[rg * TR + i][c] = o.x * o.x + o.y * o.y + o.z * o.z + o.w * o.w;
    }
    __syncthreads();
    if (t < ROWS) {
        float l2 = 0.0f;
#pragma unroll
        for (int c2 = 0; c2 < CG; ++c2) l2 += sL2[t][c2];
        nrm[base + t] = sqrtf(l2);
    }
}

// ---------------------------------------------------------------------------
// Kernel 2b: fp32 linear (layer 2) + LDS-epilogue norms.
// Same occupancy restructure: 16 rows/block, K-split staging (64 dims/stage)
// -> LDS 18.5 KB -> 8 blocks/CU. h2 bit-identical to R12's.
// ---------------------------------------------------------------------------
template <int DIN, int DOUT>
__global__ __launch_bounds__(256) void k_linear(
    const float* __restrict__ x, const float* __restrict__ W,
    float* __restrict__ out, float* __restrict__ nrm)
{
    constexpr int KT   = DIN / 2;            // 64 dims per stage (DIN=128)
    constexpr int CG   = DOUT / 4;           // 16
    constexpr int RG   = 256 / CG;           // 16
    constexpr int ROWS = 16;
    constexpr int TR   = ROWS / RG;          // 1

    __shared__ float sWt[KT][DOUT + 4];      // 64x68x4 = 17.4 KB
    __shared__ float sL2[ROWS][CG + 1];      // 1.1 KB

    const int t = threadIdx.x;
    const int rg = t / CG;
    const int c  = t % CG;
    const int base = blockIdx.x * ROWS;
    const float4* x4 = (const float4*)x;
    const float4* W4 = (const float4*)W;

    float acc[TR][4];
#pragma unroll
    for (int i = 0; i < TR; ++i)
#pragma unroll
        for (int j = 0; j < 4; ++j) acc[i][j] = 0.0f;

    for (int half = 0; half < 2; ++half) {
        if (half) __syncthreads();
        for (int i = t; i < DOUT * (KT / 4); i += 256) {
            int kk = i / (KT / 4);
            int d4 = i % (KT / 4);
            float4 w = W4[kk * (DIN / 4) + half * (KT / 4) + d4];
            sWt[4 * d4 + 0][kk] = w.x;
            sWt[4 * d4 + 1][kk] = w.y;
            sWt[4 * d4 + 2][kk] = w.z;
            sWt[4 * d4 + 3][kk] = w.w;
        }
        __syncthreads();

        for (int d4 = 0; d4 < KT / 4; ++d4) {
            const int d4g = half * (KT / 4) + d4;
            float4 xf[TR];
#pragma unroll
            for (int i = 0; i < TR; ++i)
                xf[i] = x4[(size_t)(base + rg * TR + i) * (DIN / 4) + d4g];
            float4 wf[4];
#pragma unroll
            for (int dd = 0; dd < 4; ++dd)
                wf[dd] = *(const float4*)&sWt[4 * d4 + dd][4 * c];
#pragma unroll
            for (int i = 0; i < TR; ++i) {
                acc[i][0] += xf[i].x * wf[0].x + xf[i].y * wf[1].x + xf[i].z * wf[2].x + xf[i].w * wf[3].x;
                acc[i][1] += xf[i].x * wf[0].y + xf[i].y * wf[1].y + xf[i].z * wf[2].y + xf[i].w * wf[3].y;
                acc[i][2] += xf[i].x * wf[0].z + xf[i].y * wf[1].z + xf[i].z * wf[2].z + xf[i].w * wf[3].z;
                acc[i][3] += xf[i].x * wf[0].w + xf[i].y * wf[1].w + xf[i].z * wf[2].w + xf[i].w * wf[3].w;
            }
        }
    }

#pragma unroll
    for (int i = 0; i < TR; ++i) {
        float4 o = {acc[i][0], acc[i][1], acc[i][2], acc[i][3]};
        ((float4*)out)[(size_t)(base + rg * TR + i) * CG + c] = o;
        sL2[rg * TR + i][c] = o.x * o.x + o.y * o.y + o.z * o.z + o.w * o.w;
    }
    __syncthreads();
    if (t < ROWS) {
        float l2 = 0.0f;
#pragma unroll
        for (int c2 = 0; c2 < CG; ++c2) l2 += sL2[t][c2];
        nrm[base + t] = sqrtf(l2);
    }
}

// ---------------------------------------------------------------------------
// Kernel 3a: attn layer-1 — GS=4 lazy-bf16 + CS compaction.
// [R12-passing, byte-identical]
// ---------------------------------------------------------------------------
__global__ __launch_bounds__(256) void k_attn1(
    const void* __restrict__ h16, const float* __restrict__ h32,
    const float* __restrict__ nrm,
    const int* __restrict__ cnt, const int* __restrict__ idx,
    const float* __restrict__ bias, float* __restrict__ out)
{
    constexpr int RBb = DHID * 2;   // bf16 row bytes (256)
    constexpr int RBf = DHID * 4;   // fp32 row bytes (512)
    constexpr int GS  = 4;          // 4 streams of 16 lanes

    const int bid  = blockIdx.x;
    const int b    = bid & 7;                    // batch -> XCD pinning
    const int wave = threadIdx.x >> 6;
    const int lane = threadIdx.x & 63;
    const int n    = (bid >> 3) * 4 + wave;      // one query per wave
    const int grp  = lane >> 4;
    const int gl   = lane & 15;
    const int gtop = lane | 15;
    const unsigned long long below = (1ULL << lane) - 1ULL;

    __shared__ int s_off[4][MAXDEG + 48];        // compacted bf16 byte offsets

    const int kraw = cnt[n];
    const int* __restrict__ myidx = idx + (size_t)n * MAXDEG;

    const char*  __restrict__ hb = (const char*)h16 + (size_t)b * N_ * RBb;
    const char*  __restrict__ hf = (const char*)h32 + (size_t)b * N_ * RBf;
    const float* __restrict__ nb = nrm + (size_t)b * N_;
    const int lb = gl * 16;                      // lane's bf16 byte slot (8 dims)

    // q fragment: 8 dims per lane, LAZY-unpacked bf16
    f32x2 qc[4];
    {
        const uint4 qu = *(const uint4*)(hb + (size_t)n * RBb + lb);
        qc[0] = lazy2(qu.x); qc[1] = lazy2(qu.y);
        qc[2] = lazy2(qu.z); qc[3] = lazy2(qu.w);
    }

    // fixed-order packed dot; identical sequence for self-init and loop
    auto dot8 = [](const f32x2* q, const f32x2* c) -> float {
        f32x2 pa = q[0] * c[0];
        f32x2 pb = q[1] * c[1];
        pa += q[2] * c[2];
        pb += q[3] * c[3];
        f32x2 t = pa + pb;
        return t.x + t.y;
    };

    // self-score init: m = ||q'||^2 (identical op order to loop dot)
    float m;
    {
        float p = dot8(qc, qc);
        p = dpp_reduce<16>(p);
        const float pb = __shfl(p, gtop, 64);
        m = (pb != 0.0f) ? pb : -INFINITY;
    }
    float mt = m - 100.0f;

    // Cauchy-Schwarz ballot-compaction of the neighbor list
    int kk = 0;
    {
        const bool keepall = (m == -INFINITY);
        const float sq = keepall ? 0.0f : sqrtf(m) * 1.001f;
        for (int j0 = 0; j0 < kraw; j0 += 64) {
            const int j = j0 + lane;
            bool keep = false;
            int id = 0;
            if (j < kraw) {
                id = myidx[j];
                keep = keepall || (nb[id] * sq * 1.02f + 4.0f > mt);
            }
            const unsigned long long mk = __ballot(keep);
            if (keep) s_off[wave][kk + __popcll(mk & below)] = id * RBb;
            kk += __popcll(mk);
        }
        for (int z = kk + lane; z < kk + 48; z += 64) s_off[wave][z] = 0;
    }

    float s = 0.0f;
    float acc8[8];
#pragma unroll
    for (int i = 0; i < 8; ++i) acc8[i] = 0.0f;

    // taken path accumulates from the FP32 row (off = bf16 offset; x2 = fp32)
    auto process = [&](const uint4 cur, int off) {
        f32x2 c[4] = {lazy2(cur.x), lazy2(cur.y), lazy2(cur.z), lazy2(cur.w)};
        float p = dot8(qc, c);
        p = dpp_reduce<16>(p);
        if (__builtin_expect((__ballot(p > mt) & 0x8000800080008000ULL) != 0ULL, 0)) {
            const float pb = __shfl(p, gtop, 64);
            const bool valid = (pb != 0.0f);      // dot==0 => masked (torch)
            const float pm   = valid ? pb : m;
            const float newm = fmaxf(m, pm);
            const float f = (m == newm) ? 1.0f : __expf(m - newm);
            const float e = valid ? __expf(pb - newm) : 0.0f;
            s = s * f + e;
            const float4* fr = (const float4*)(hf + 2 * (size_t)off) + 2 * gl;
            const float4 lo = fr[0], hi = fr[1];
            const float f8[8] = {lo.x, lo.y, lo.z, lo.w, hi.x, hi.y, hi.z, hi.w};
#pragma unroll
            for (int i = 0; i < 8; ++i) acc8[i] = acc8[i] * f + e * f8[i];
            m = newm;
            mt = m - 100.0f;
        }
    };

    // depth-2 data + depth-4 offset pipeline over the COMPACTED list
    {
        uint4 r0, r1, r2;
        int u0, u1, u2, oA, oB, oC;
        oA = s_off[wave][grp + 2 * GS];
        oB = s_off[wave][grp + 3 * GS];
        u0 = s_off[wave][grp];
        r0 = *(const uint4*)(hb + u0 + lb);
        u1 = s_off[wave][grp + GS];
        r1 = *(const uint4*)(hb + u1 + lb);
        int j = grp;
        while (j < kk) {
            oC = s_off[wave][j + 4 * GS];
            u2 = oA; r2 = *(const uint4*)(hb + u2 + lb);
            process(r0, u0);
            j += GS; if (j >= kk) break;
            oA = s_off[wave][j + 4 * GS];
            u0 = oB; r0 = *(const uint4*)(hb + u0 + lb);
            process(r1, u1);
            j += GS; if (j >= kk) break;
            oB = s_off[wave][j + 4 * GS];
            u1 = oC; r1 = *(const uint4*)(hb + u1 + lb);
            process(r2, u2);
            j += GS;
        }
    }

    // merge the 4 subgroup states (xor 16, 32)
#pragma unroll
    for (int mask = 16; mask <= 32; mask <<= 1) {
        const float m2 = __shfl_xor(m, mask, 64);
        const float s2 = __shfl_xor(s, mask, 64);
        float a2[8];
#pragma unroll
        for (int i = 0; i < 8; ++i) a2[i] = __shfl_xor(acc8[i], mask, 64);
        const float mm = fmaxf(m, m2);
        const float f1 = (m  == mm) ? 1.0f : __expf(m  - mm);
        const float f2 = (m2 == mm) ? 1.0f : __expf(m2 - mm);
        s = s * f1 + s2 * f2;
#pragma unroll
        for (int i = 0; i < 8; ++i) acc8[i] = acc8[i] * f1 + a2[i] * f2;
        m = mm;
    }

    if (s > 0.0f) {
        if (grp == 0) {
            const float4* bias4 = (const float4*)bias;
            const float4 b0 = bias4[2 * gl], b1 = bias4[2 * gl + 1];
            const float bi[8] = {b0.x, b0.y, b0.z, b0.w, b1.x, b1.y, b1.z, b1.w};
            const float inv = 1.0f / s;
            float4 lo, hi;
            lo.x = fmaxf(acc8[0] * inv + bi[0], 0.0f);
            lo.y = fmaxf(acc8[1] * inv + bi[1], 0.0f);
            lo.z = fmaxf(acc8[2] * inv + bi[2], 0.0f);
            lo.w = fmaxf(acc8[3] * inv + bi[3], 0.0f);
            hi.x = fmaxf(acc8[4] * inv + bi[4], 0.0f);
            hi.y = fmaxf(acc8[5] * inv + bi[5], 0.0f);
            hi.z = fmaxf(acc8[6] * inv + bi[6], 0.0f);
            hi.w = fmaxf(acc8[7] * inv + bi[7], 0.0f);
            float4* orow = (float4*)out + ((size_t)b * N_ + n) * (DHID / 4) + 2 * gl;
            orow[0] = lo;
            orow[1] = hi;
        }
    } else {
        // RARE (all masked): uniform softmax -> column mean of fp32 h[b]
        const float4* hf4 = (const float4*)hf;
        const int sl = lane % 32;
        const int rs = lane / 32;
        float4 a = {0.0f, 0.0f, 0.0f, 0.0f};
        for (int row = rs; row < N_; row += 2) {
            float4 v = hf4[(size_t)row * 32 + sl];
            a.x += v.x; a.y += v.y; a.z += v.z; a.w += v.w;
        }
        a.x += __shfl_xor(a.x, 32, 64);
        a.y += __shfl_xor(a.y, 32, 64);
        a.z += __shfl_xor(a.z, 32, 64);
        a.w += __shfl_xor(a.w, 32, 64);
        if (lane < 32) {
            constexpr float invN = 1.0f / (float)N_;
            const float4 bi = ((const float4*)bias)[sl];
            float4 o;
            o.x = fmaxf(a.x * invN + bi.x, 0.0f);
            o.y = fmaxf(a.y * invN + bi.y, 0.0f);
            o.z = fmaxf(a.z * invN + bi.z, 0.0f);
            o.w = fmaxf(a.w * invN + bi.w, 0.0f);
            ((float4*)out)[((size_t)b * N_ + n) * 32 + sl] = o;
        }
    }
}

// ---------------------------------------------------------------------------
// Kernel 3b: attn layer-2, fp32, GS=4 + CS compaction.
// [R12-passing, byte-identical]
// ---------------------------------------------------------------------------
__global__ __launch_bounds__(256) void k_attn2(
    const float* __restrict__ h, const float* __restrict__ nrm,
    const int* __restrict__ cnt, const int* __restrict__ idx,
    const float* __restrict__ bias, float* __restrict__ out)
{
    constexpr int D  = DOUT2;
    constexpr int V  = D / 4;                    // 16
    constexpr int GS = 4;                        // 4 streams of 16 lanes
    constexpr int RB = D * 4;                    // 256

    const int bid  = blockIdx.x;
    const int b    = bid & 7;
    const int wave = threadIdx.x >> 6;
    const int lane = threadIdx.x & 63;
    const int n    = (bid >> 3) * 4 + wave;
    const int grp  = lane >> 4;
    const int gl   = lane & 15;
    const int gtop = lane | 15;
    const unsigned long long below = (1ULL << lane) - 1ULL;

    __shared__ int s_off[4][MAXDEG + 48];

    const int kraw = cnt[n];
    const int* __restrict__ myidx = idx + (size_t)n * MAXDEG;

    const char*  __restrict__ hb = (const char*)h + (size_t)b * N_ * RB;
    const float* __restrict__ nb = nrm + (size_t)b * N_;
    const int lb = gl * 16;                      // dims [4gl, 4gl+4)

    float4 qf;
    qf = *(const float4*)(hb + (size_t)n * RB + lb);
    f32x2 q01, q23;
    q01.x = qf.x; q01.y = qf.y;
    q23.x = qf.z; q23.y = qf.w;

    auto dotc = [&](const float4 c) -> float {
        f32x2 c01, c23;
        c01.x = c.x; c01.y = c.y;
        c23.x = c.z; c23.y = c.w;
        f32x2 t = q01 * c01;
        t += q23 * c23;
        return t.x + t.y;
    };

    float m;
    {
        float p = dotc(qf);
        p = dpp_reduce<16>(p);
        const float pb = __shfl(p, gtop, 64);
        m = (pb != 0.0f) ? pb : -INFINITY;
    }
    float mt = m - 100.0f;

    // Cauchy-Schwarz ballot-compaction
    int kk = 0;
    {
        const bool keepall = (m == -INFINITY);
        const float sq = keepall ? 0.0f : sqrtf(m) * 1.001f;
        for (int j0 = 0; j0 < kraw; j0 += 64) {
            const int j = j0 + lane;
            bool keep = false;
            int id = 0;
            if (j < kraw) {
                id = myidx[j];
                keep = keepall || (nb[id] * sq * 1.01f + 4.0f > mt);
            }
            const unsigned long long mk = __ballot(keep);
            if (keep) s_off[wave][kk + __popcll(mk & below)] = id * RB;
            kk += __popcll(mk);
        }
        for (int z = kk + lane; z < kk + 48; z += 64) s_off[wave][z] = 0;
    }

    float s = 0.0f;
    float4 acc = {0.0f, 0.0f, 0.0f, 0.0f};

    auto process = [&](const float4 cur) {
        float p = dotc(cur);
        p = dpp_reduce<16>(p);
        if (__builtin_expect((__ballot(p > mt) & 0x8000800080008000ULL) != 0ULL, 0)) {
            const float pb = __shfl(p, gtop, 64);
            const bool valid = (pb != 0.0f);
            const float pm   = valid ? pb : m;
            const float newm = fmaxf(m, pm);
            const float f = (m == newm) ? 1.0f : __expf(m - newm);
            const float e = valid ? __expf(pb - newm) : 0.0f;
            s = s * f + e;
            acc.x = acc.x * f + e * cur.x;
            acc.y = acc.y * f + e * cur.y;
            acc.z = acc.z * f + e * cur.z;
            acc.w = acc.w * f + e * cur.w;
            m = newm;
            mt = m - 100.0f;
        }
    };

    // depth-2 data + depth-4 offset pipeline over the COMPACTED list
    {
        float4 r0, r1, r2;
        int oA, oB, oC;
        oA = s_off[wave][grp + 2 * GS];
        oB = s_off[wave][grp + 3 * GS];
        r0 = *(const float4*)(hb + s_off[wave][grp] + lb);
        r1 = *(const float4*)(hb + s_off[wave][grp + GS] + lb);
        int j = grp;
        while (j < kk) {
            oC = s_off[wave][j + 4 * GS];
            r2 = *(const float4*)(hb + oA + lb);
            process(r0);
            j += GS; if (j >= kk) break;
            oA = s_off[wave][j + 4 * GS];
            r0 = *(const float4*)(hb + oB + lb);
            process(r1);
            j += GS; if (j >= kk) break;
            oB = s_off[wave][j + 4 * GS];
            r1 = *(const float4*)(hb + oC + lb);
            process(r2);
            j += GS;
        }
    }

    // merge the 4 subgroup states (xor 16, 32)
#pragma unroll
    for (int mask = 16; mask <= 32; mask <<= 1) {
        const float m2 = __shfl_xor(m, mask, 64);
        const float s2 = __shfl_xor(s, mask, 64);
        float4 a2;
        a2.x = __shfl_xor(acc.x, mask, 64);
        a2.y = __shfl_xor(acc.y, mask, 64);
        a2.z = __shfl_xor(acc.z, mask, 64);
        a2.w = __shfl_xor(acc.w, mask, 64);
        const float mm = fmaxf(m, m2);
        const float f1 = (m  == mm) ? 1.0f : __expf(m  - mm);
        const float f2 = (m2 == mm) ? 1.0f : __expf(m2 - mm);
        s = s * f1 + s2 * f2;
        acc.x = acc.x * f1 + a2.x * f2;
        acc.y = acc.y * f1 + a2.y * f2;
        acc.z = acc.z * f1 + a2.z * f2;
        acc.w = acc.w * f1 + a2.w * f2;
        m = mm;
    }

    if (s > 0.0f) {
        if (grp == 0) {
            const float4 bi = ((const float4*)bias)[gl];
            const float inv = 1.0f / s;
            float4 o;
            o.x = acc.x * inv + bi.x;
            o.y = acc.y * inv + bi.y;
            o.z = acc.z * inv + bi.z;
            o.w = acc.w * inv + bi.w;
            ((float4*)out)[((size_t)b * N_ + n) * V + gl] = o;
        }
    } else {
        const float4* hb4 = (const float4*)hb;
        const int sl = lane % V;
        const int rs = lane / V;
        float4 a = {0.0f, 0.0f, 0.0f, 0.0f};
        for (int row = rs; row < N_; row += 4) {
            float4 v = hb4[(size_t)row * V + sl];
            a.x += v.x; a.y += v.y; a.z += v.z; a.w += v.w;
        }
#pragma unroll
        for (int mask = 16; mask <= 32; mask <<= 1) {
            a.x += __shfl_xor(a.x, mask, 64);
            a.y += __shfl_xor(a.y, mask, 64);
            a.z += __shfl_xor(a.z, mask, 64);
            a.w += __shfl_xor(a.w, mask, 64);
        }
        if (lane < V) {
            constexpr float invN = 1.0f / (float)N_;
            const float4 bi = ((const float4*)bias)[sl];
            float4 o;
            o.x = a.x * invN + bi.x;
            o.y = a.y * invN + bi.y;
            o.z = a.z * invN + bi.z;
            o.w = a.w * invN + bi.w;
            ((float4*)out)[((size_t)b * N_ + n) * V + sl] = o;
        }
    }
}

// ---------------------------------------------------------------------------
// Launch
// ---------------------------------------------------------------------------
extern "C" void kernel_launch(void* const* d_in, const int* in_sizes, int n_in,
                              void* d_out, int out_size, void* d_ws, size_t ws_size,
                              hipStream_t stream) {
    (void)in_sizes; (void)n_in; (void)out_size; (void)ws_size;

    const float* flow_x = (const float*)d_in[0];
    const float* graph  = (const float*)d_in[1];
    const float* W1     = (const float*)d_in[2];
    const float* b1     = (const float*)d_in[3];
    const float* W2     = (const float*)d_in[4];
    const float* b2     = (const float*)d_in[5];
    float* out = (float*)d_out;

    char* p = (char*)d_ws;
    auto carve = [&](size_t bytes) -> void* {
        void* r = (void*)p;
        p += (bytes + 255) & ~(size_t)255;
        return r;
    };
    int*   nbr_cnt = (int*)carve((size_t)N_ * sizeof(int));
    int*   nbr_idx = (int*)carve((size_t)N_ * MAXDEG * sizeof(int));
    float* h1      = (float*)carve((size_t)B_ * N_ * DHID * sizeof(float));
    void*  h1b     = carve((size_t)B_ * N_ * DHID * 2);   // bf16 copy
    float* x2      = (float*)carve((size_t)B_ * N_ * DHID * sizeof(float));
    float* h2      = (float*)carve((size_t)B_ * N_ * DOUT2 * sizeof(float));
    float* nrm1    = (float*)carve((size_t)B_ * N_ * sizeof(float));
    float* nrm2    = (float*)carve((size_t)B_ * N_ * sizeof(float));

    // 1. adjacency -> neighbor lists
    k_build_csr<<<N_ / 4, 256, 0, stream>>>(graph, nbr_cnt, nbr_idx);

    // 2. layer 1 linear: 16 rows/block, K-split LDS (32 waves/CU capable)
    k_linear1<<<(B_ * N_) / 16, 256, 0, stream>>>(flow_x, W1, h1, h1b, nrm1);

    // 3. layer 1 attention: CS-compacted bf16 gather/score, fp32 acc -> x2
    k_attn1<<<N_ * B_ / 4, 256, 0, stream>>>(h1b, h1, nrm1, nbr_cnt, nbr_idx, b1, x2);

    // 4. layer 2 linear: 16 rows/block, K-split LDS
    k_linear<DHID, DOUT2><<<(B_ * N_) / 16, 256, 0, stream>>>(x2, W2, h2, nrm2);

    // 5. layer 2 attention (fp32, GS=4, CS-compacted) -> d_out
    k_attn2<<<N_ * B_ / 4, 256, 0, stream>>>(h2, nrm2, nbr_cnt, nbr_idx, b2, out);
}

// Round 15
// 221.475 us; speedup vs baseline: 1.0216x; 1.0216x over previous
//
#include <hip/hip_runtime.h>
#include <cmath>

// Problem constants
#define B_   8
#define N_   4096
#define DIN1 64
#define DHID 128
#define DOUT2 64
#define MAXDEG 256

typedef float f32x2 __attribute__((ext_vector_type(2)));

// ---------------- bf16 helpers -------------------------------------------
__device__ __forceinline__ unsigned pack2bf(float a, float b) {
    unsigned ua = __float_as_uint(a), ub = __float_as_uint(b);
    ua = (ua + 0x7FFFu + ((ua >> 16) & 1u)) >> 16;
    ub = (ub + 0x7FFFu + ((ub >> 16) & 1u)) & 0xFFFF0000u;
    return ua | ub;          // lo half = a, hi half = b
}
// LAZY unpack into a packed float2: hi element keeps low-16 garbage bits
// (<=2^-8 relative mantissa perturbation, exponent untouched). Deterministic;
// identical for q-init and loop -> self score bit-exact.
__device__ __forceinline__ f32x2 lazy2(unsigned u) {
    f32x2 r;
    r.x = __uint_as_float(u << 16);
    r.y = __uint_as_float(u);
    return r;
}

template <int SH>
__device__ __forceinline__ float dpp_shr_add(float p) {
    int t = __builtin_amdgcn_update_dpp(0, __float_as_int(p),
                                        0x110 | SH, 0xF, 0xF, true);
    return p + __int_as_float(t);
}
// Row-sum lands on the TOP lane of each GRPL-lane subgroup.
template <int GRPL>
__device__ __forceinline__ float dpp_reduce(float p) {
    if constexpr (GRPL == 16) p = dpp_shr_add<8>(p);
    p = dpp_shr_add<4>(p);
    p = dpp_shr_add<2>(p);
    p = dpp_shr_add<1>(p);
    return p;   // valid on lane GRPL-1 of each subgroup
}

// ---------------------------------------------------------------------------
// Kernel 1: adjacency -> neighbor lists. Wave per row, ballot compaction.
// ---------------------------------------------------------------------------
__global__ __launch_bounds__(256) void k_build_csr(
    const float* __restrict__ graph, int* __restrict__ cnt, int* __restrict__ idx)
{
    const int wave = threadIdx.x >> 6;
    const int lane = threadIdx.x & 63;
    const int n = blockIdx.x * 4 + wave;
    const unsigned long long below_mask = (1ULL << lane) - 1ULL;

    const float4* __restrict__ row4 = (const float4*)(graph + (size_t)n * N_);
    int* __restrict__ myidx = idx + (size_t)n * MAXDEG;

    int base = 0;
    for (int it = 0; it < N_ / 256; ++it) {
        const int i4 = it * 64 + lane;
        float4 g = row4[i4];
        const int e = 4 * i4;
#pragma unroll
        for (int c = 0; c < 4; ++c) {
            const float gc = (c == 0) ? g.x : (c == 1) ? g.y : (c == 2) ? g.z : g.w;
            const unsigned long long mk = __ballot(gc != 0.0f);
            const int pos = base + __popcll(mk & below_mask);
            if (gc != 0.0f && pos < MAXDEG) myidx[pos] = e + c;
            base += __popcll(mk);
        }
    }
    if (lane == 0) cnt[n] = (base < MAXDEG) ? base : MAXDEG;
}

// ---------------------------------------------------------------------------
// Kernel 2a: linear1, DUAL WRITE (fp32 + bf16) + LDS-epilogue norms.
// [R12-proven, byte-identical]
// ---------------------------------------------------------------------------
__global__ __launch_bounds__(256) void k_linear1(
    const float* __restrict__ x, const float* __restrict__ W,
    float* __restrict__ out, void* __restrict__ outb, float* __restrict__ nrm)
{
    constexpr int DIN = DIN1, DOUT = DHID;
    constexpr int CG = DOUT / 4;      // 32
    constexpr int RG = 256 / CG;      // 8
    constexpr int TR = 32 / RG;       // 4

    __shared__ float sWt[DIN][DOUT + 4];
    __shared__ float sL2[32][CG + 1];

    const int t = threadIdx.x;
    const float4* W4 = (const float4*)W;
    for (int i = t; i < DOUT * (DIN / 4); i += 256) {
        int kk = i / (DIN / 4);
        int d4 = i % (DIN / 4);
        float4 w = W4[i];
        sWt[4 * d4 + 0][kk] = w.x;
        sWt[4 * d4 + 1][kk] = w.y;
        sWt[4 * d4 + 2][kk] = w.z;
        sWt[4 * d4 + 3][kk] = w.w;
    }
    __syncthreads();

    const int rg = t / CG;
    const int c  = t % CG;
    const int base = blockIdx.x * 32;
    const float4* x4 = (const float4*)x;

    float acc[TR][4];
#pragma unroll
    for (int i = 0; i < TR; ++i)
#pragma unroll
        for (int j = 0; j < 4; ++j) acc[i][j] = 0.0f;

    for (int d4 = 0; d4 < DIN / 4; ++d4) {
        float4 xf[TR];
#pragma unroll
        for (int i = 0; i < TR; ++i)
            xf[i] = x4[(size_t)(base + rg * TR + i) * (DIN / 4) + d4];
        float4 wf[4];
#pragma unroll
        for (int dd = 0; dd < 4; ++dd)
            wf[dd] = *(const float4*)&sWt[4 * d4 + dd][4 * c];
#pragma unroll
        for (int i = 0; i < TR; ++i) {
            acc[i][0] += xf[i].x * wf[0].x + xf[i].y * wf[1].x + xf[i].z * wf[2].x + xf[i].w * wf[3].x;
            acc[i][1] += xf[i].x * wf[0].y + xf[i].y * wf[1].y + xf[i].z * wf[2].y + xf[i].w * wf[3].y;
            acc[i][2] += xf[i].x * wf[0].z + xf[i].y * wf[1].z + xf[i].z * wf[2].z + xf[i].w * wf[3].z;
            acc[i][3] += xf[i].x * wf[0].w + xf[i].y * wf[1].w + xf[i].z * wf[2].w + xf[i].w * wf[3].w;
        }
    }

#pragma unroll
    for (int i = 0; i < TR; ++i) {
        const size_t row = (size_t)(base + rg * TR + i);
        float4 o = {acc[i][0], acc[i][1], acc[i][2], acc[i][3]};
        ((float4*)out)[row * CG + c] = o;
        uint2 ob = {pack2bf(o.x, o.y), pack2bf(o.z, o.w)};
        *(uint2*)((char*)outb + row * (DOUT * 2) + c * 8) = ob;
        sL2[rg * TR + i][c] = o.x * o.x + o.y * o.y + o.z * o.z + o.w * o.w;
    }
    __syncthreads();
    if (t < 32) {
        float l2 = 0.0f;
#pragma unroll
        for (int c2 = 0; c2 < CG; ++c2) l2 += sL2[t][c2];
        nrm[base + t] = sqrtf(l2);
    }
}

// ---------------------------------------------------------------------------
// Kernel 2b: fp32 register-tiled linear (layer 2) + LDS-epilogue norms.
// [R12-proven, byte-identical]
// ---------------------------------------------------------------------------
template <int DIN, int DOUT>
__global__ __launch_bounds__(256) void k_linear(
    const float* __restrict__ x, const float* __restrict__ W,
    float* __restrict__ out, float* __restrict__ nrm)
{
    constexpr int CG = DOUT / 4;
    constexpr int RG = 256 / CG;
    constexpr int TR = 32 / RG;

    __shared__ float sWt[DIN][DOUT + 4];
    __shared__ float sL2[32][CG + 1];

    const int t = threadIdx.x;
    const float4* W4 = (const float4*)W;
    for (int i = t; i < DOUT * (DIN / 4); i += 256) {
        int kk = i / (DIN / 4);
        int d4 = i % (DIN / 4);
        float4 w = W4[i];
        sWt[4 * d4 + 0][kk] = w.x;
        sWt[4 * d4 + 1][kk] = w.y;
        sWt[4 * d4 + 2][kk] = w.z;
        sWt[4 * d4 + 3][kk] = w.w;
    }
    __syncthreads();

    const int rg = t / CG;
    const int c  = t % CG;
    const int base = blockIdx.x * 32;
    const float4* x4 = (const float4*)x;

    float acc[TR][4];
#pragma unroll
    for (int i = 0; i < TR; ++i)
#pragma unroll
        for (int j = 0; j < 4; ++j) acc[i][j] = 0.0f;

    for (int d4 = 0; d4 < DIN / 4; ++d4) {
        float4 xf[TR];
#pragma unroll
        for (int i = 0; i < TR; ++i)
            xf[i] = x4[(size_t)(base + rg * TR + i) * (DIN / 4) + d4];
        float4 wf[4];
#pragma unroll
        for (int dd = 0; dd < 4; ++dd)
            wf[dd] = *(const float4*)&sWt[4 * d4 + dd][4 * c];
#pragma unroll
        for (int i = 0; i < TR; ++i) {
            acc[i][0] += xf[i].x * wf[0].x + xf[i].y * wf[1].x + xf[i].z * wf[2].x + xf[i].w * wf[3].x;
            acc[i][1] += xf[i].x * wf[0].y + xf[i].y * wf[1].y + xf[i].z * wf[2].y + xf[i].w * wf[3].y;
            acc[i][2] += xf[i].x * wf[0].z + xf[i].y * wf[1].z + xf[i].z * wf[2].z + xf[i].w * wf[3].z;
            acc[i][3] += xf[i].x * wf[0].w + xf[i].y * wf[1].w + xf[i].z * wf[2].w + xf[i].w * wf[3].w;
        }
    }

#pragma unroll
    for (int i = 0; i < TR; ++i) {
        float4 o = {acc[i][0], acc[i][1], acc[i][2], acc[i][3]};
        ((float4*)out)[(size_t)(base + rg * TR + i) * CG + c] = o;
        sL2[rg * TR + i][c] = o.x * o.x + o.y * o.y + o.z * o.z + o.w * o.w;
    }
    __syncthreads();
    if (t < 32) {
        float l2 = 0.0f;
#pragma unroll
        for (int c2 = 0; c2 < CG; ++c2) l2 += sL2[t][c2];
        nrm[base + t] = sqrtf(l2);
    }
}

// ---------------------------------------------------------------------------
// Kernel 3a: attn layer-1 — GS=4 lazy-bf16 + CS compaction.
// [R12-passing, byte-identical]
// ---------------------------------------------------------------------------
__global__ __launch_bounds__(256) void k_attn1(
    const void* __restrict__ h16, const float* __restrict__ h32,
    const float* __restrict__ nrm,
    const int* __restrict__ cnt, const int* __restrict__ idx,
    const float* __restrict__ bias, float* __restrict__ out)
{
    constexpr int RBb = DHID * 2;   // bf16 row bytes (256)
    constexpr int RBf = DHID * 4;   // fp32 row bytes (512)
    constexpr int GS  = 4;          // 4 streams of 16 lanes

    const int bid  = blockIdx.x;
    const int b    = bid & 7;                    // batch -> XCD pinning
    const int wave = threadIdx.x >> 6;
    const int lane = threadIdx.x & 63;
    const int n    = (bid >> 3) * 4 + wave;      // one query per wave
    const int grp  = lane >> 4;
    const int gl   = lane & 15;
    const int gtop = lane | 15;
    const unsigned long long below = (1ULL << lane) - 1ULL;

    __shared__ int s_off[4][MAXDEG + 48];        // compacted bf16 byte offsets

    const int kraw = cnt[n];
    const int* __restrict__ myidx = idx + (size_t)n * MAXDEG;

    const char*  __restrict__ hb = (const char*)h16 + (size_t)b * N_ * RBb;
    const char*  __restrict__ hf = (const char*)h32 + (size_t)b * N_ * RBf;
    const float* __restrict__ nb = nrm + (size_t)b * N_;
    const int lb = gl * 16;                      // lane's bf16 byte slot (8 dims)

    // q fragment: 8 dims per lane, LAZY-unpacked bf16
    f32x2 qc[4];
    {
        const uint4 qu = *(const uint4*)(hb + (size_t)n * RBb + lb);
        qc[0] = lazy2(qu.x); qc[1] = lazy2(qu.y);
        qc[2] = lazy2(qu.z); qc[3] = lazy2(qu.w);
    }

    // fixed-order packed dot; identical sequence for self-init and loop
    auto dot8 = [](const f32x2* q, const f32x2* c) -> float {
        f32x2 pa = q[0] * c[0];
        f32x2 pb = q[1] * c[1];
        pa += q[2] * c[2];
        pb += q[3] * c[3];
        f32x2 t = pa + pb;
        return t.x + t.y;
    };

    // self-score init: m = ||q'||^2 (identical op order to loop dot)
    float m;
    {
        float p = dot8(qc, qc);
        p = dpp_reduce<16>(p);
        const float pb = __shfl(p, gtop, 64);
        m = (pb != 0.0f) ? pb : -INFINITY;
    }
    float mt = m - 100.0f;

    // Cauchy-Schwarz ballot-compaction of the neighbor list
    int kk = 0;
    {
        const bool keepall = (m == -INFINITY);
        const float sq = keepall ? 0.0f : sqrtf(m) * 1.001f;
        for (int j0 = 0; j0 < kraw; j0 += 64) {
            const int j = j0 + lane;
            bool keep = false;
            int id = 0;
            if (j < kraw) {
                id = myidx[j];
                keep = keepall || (nb[id] * sq * 1.02f + 4.0f > mt);
            }
            const unsigned long long mk = __ballot(keep);
            if (keep) s_off[wave][kk + __popcll(mk & below)] = id * RBb;
            kk += __popcll(mk);
        }
        for (int z = kk + lane; z < kk + 48; z += 64) s_off[wave][z] = 0;
    }

    float s = 0.0f;
    float acc8[8];
#pragma unroll
    for (int i = 0; i < 8; ++i) acc8[i] = 0.0f;

    // taken path accumulates from the FP32 row (off = bf16 offset; x2 = fp32)
    auto process = [&](const uint4 cur, int off) {
        f32x2 c[4] = {lazy2(cur.x), lazy2(cur.y), lazy2(cur.z), lazy2(cur.w)};
        float p = dot8(qc, c);
        p = dpp_reduce<16>(p);
        if (__builtin_expect((__ballot(p > mt) & 0x8000800080008000ULL) != 0ULL, 0)) {
            const float pb = __shfl(p, gtop, 64);
            const bool valid = (pb != 0.0f);      // dot==0 => masked (torch)
            const float pm   = valid ? pb : m;
            const float newm = fmaxf(m, pm);
            const float f = (m == newm) ? 1.0f : __expf(m - newm);
            const float e = valid ? __expf(pb - newm) : 0.0f;
            s = s * f + e;
            const float4* fr = (const float4*)(hf + 2 * (size_t)off) + 2 * gl;
            const float4 lo = fr[0], hi = fr[1];
            const float f8[8] = {lo.x, lo.y, lo.z, lo.w, hi.x, hi.y, hi.z, hi.w};
#pragma unroll
            for (int i = 0; i < 8; ++i) acc8[i] = acc8[i] * f + e * f8[i];
            m = newm;
            mt = m - 100.0f;
        }
    };

    // depth-2 data + depth-4 offset pipeline over the COMPACTED list
    {
        uint4 r0, r1, r2;
        int u0, u1, u2, oA, oB, oC;
        oA = s_off[wave][grp + 2 * GS];
        oB = s_off[wave][grp + 3 * GS];
        u0 = s_off[wave][grp];
        r0 = *(const uint4*)(hb + u0 + lb);
        u1 = s_off[wave][grp + GS];
        r1 = *(const uint4*)(hb + u1 + lb);
        int j = grp;
        while (j < kk) {
            oC = s_off[wave][j + 4 * GS];
            u2 = oA; r2 = *(const uint4*)(hb + u2 + lb);
            process(r0, u0);
            j += GS; if (j >= kk) break;
            oA = s_off[wave][j + 4 * GS];
            u0 = oB; r0 = *(const uint4*)(hb + u0 + lb);
            process(r1, u1);
            j += GS; if (j >= kk) break;
            oB = s_off[wave][j + 4 * GS];
            u1 = oC; r1 = *(const uint4*)(hb + u1 + lb);
            process(r2, u2);
            j += GS;
        }
    }

    // merge the 4 subgroup states (xor 16, 32)
#pragma unroll
    for (int mask = 16; mask <= 32; mask <<= 1) {
        const float m2 = __shfl_xor(m, mask, 64);
        const float s2 = __shfl_xor(s, mask, 64);
        float a2[8];
#pragma unroll
        for (int i = 0; i < 8; ++i) a2[i] = __shfl_xor(acc8[i], mask, 64);
        const float mm = fmaxf(m, m2);
        const float f1 = (m  == mm) ? 1.0f : __expf(m  - mm);
        const float f2 = (m2 == mm) ? 1.0f : __expf(m2 - mm);
        s = s * f1 + s2 * f2;
#pragma unroll
        for (int i = 0; i < 8; ++i) acc8[i] = acc8[i] * f1 + a2[i] * f2;
        m = mm;
    }

    if (s > 0.0f) {
        if (grp == 0) {
            const float4* bias4 = (const float4*)bias;
            const float4 b0 = bias4[2 * gl], b1 = bias4[2 * gl + 1];
            const float bi[8] = {b0.x, b0.y, b0.z, b0.w, b1.x, b1.y, b1.z, b1.w};
            const float inv = 1.0f / s;
            float4 lo, hi;
            lo.x = fmaxf(acc8[0] * inv + bi[0], 0.0f);
            lo.y = fmaxf(acc8[1] * inv + bi[1], 0.0f);
            lo.z = fmaxf(acc8[2] * inv + bi[2], 0.0f);
            lo.w = fmaxf(acc8[3] * inv + bi[3], 0.0f);
            hi.x = fmaxf(acc8[4] * inv + bi[4], 0.0f);
            hi.y = fmaxf(acc8[5] * inv + bi[5], 0.0f);
            hi.z = fmaxf(acc8[6] * inv + bi[6], 0.0f);
            hi.w = fmaxf(acc8[7] * inv + bi[7], 0.0f);
            float4* orow = (float4*)out + ((size_t)b * N_ + n) * (DHID / 4) + 2 * gl;
            orow[0] = lo;
            orow[1] = hi;
        }
    } else {
        // RARE (all masked): uniform softmax -> column mean of fp32 h[b]
        const float4* hf4 = (const float4*)hf;
        const int sl = lane % 32;
        const int rs = lane / 32;
        float4 a = {0.0f, 0.0f, 0.0f, 0.0f};
        for (int row = rs; row < N_; row += 2) {
            float4 v = hf4[(size_t)row * 32 + sl];
            a.x += v.x; a.y += v.y; a.z += v.z; a.w += v.w;
        }
        a.x += __shfl_xor(a.x, 32, 64);
        a.y += __shfl_xor(a.y, 32, 64);
        a.z += __shfl_xor(a.z, 32, 64);
        a.w += __shfl_xor(a.w, 32, 64);
        if (lane < 32) {
            constexpr float invN = 1.0f / (float)N_;
            const float4 bi = ((const float4*)bias)[sl];
            float4 o;
            o.x = fmaxf(a.x * invN + bi.x, 0.0f);
            o.y = fmaxf(a.y * invN + bi.y, 0.0f);
            o.z = fmaxf(a.z * invN + bi.z, 0.0f);
            o.w = fmaxf(a.w * invN + bi.w, 0.0f);
            ((float4*)out)[((size_t)b * N_ + n) * 32 + sl] = o;
        }
    }
}

// ---------------------------------------------------------------------------
// Kernel 3b: attn layer-2, fp32 scoring (REQUIRED — two independent
// low-precision ports failed: R2 f16/dot2, R14 lazy-bf16; h2 rows share a
// large common component via E[relu]>0, so cross-score gaps can be within
// low-precision noise), GS=4 + CS compaction. [R12-passing, byte-identical]
// ---------------------------------------------------------------------------
__global__ __launch_bounds__(256) void k_attn2(
    const float* __restrict__ h, const float* __restrict__ nrm,
    const int* __restrict__ cnt, const int* __restrict__ idx,
    const float* __restrict__ bias, float* __restrict__ out)
{
    constexpr int D  = DOUT2;
    constexpr int V  = D / 4;                    // 16
    constexpr int GS = 4;                        // 4 streams of 16 lanes
    constexpr int RB = D * 4;                    // 256

    const int bid  = blockIdx.x;
    const int b    = bid & 7;
    const int wave = threadIdx.x >> 6;
    const int lane = threadIdx.x & 63;
    const int n    = (bid >> 3) * 4 + wave;
    const int grp  = lane >> 4;
    const int gl   = lane & 15;
    const int gtop = lane | 15;
    const unsigned long long below = (1ULL << lane) - 1ULL;

    __shared__ int s_off[4][MAXDEG + 48];

    const int kraw = cnt[n];
    const int* __restrict__ myidx = idx + (size_t)n * MAXDEG;

    const char*  __restrict__ hb = (const char*)h + (size_t)b * N_ * RB;
    const float* __restrict__ nb = nrm + (size_t)b * N_;
    const int lb = gl * 16;                      // dims [4gl, 4gl+4)

    float4 qf;
    qf = *(const float4*)(hb + (size_t)n * RB + lb);
    f32x2 q01, q23;
    q01.x = qf.x; q01.y = qf.y;
    q23.x = qf.z; q23.y = qf.w;

    auto dotc = [&](const float4 c) -> float {
        f32x2 c01, c23;
        c01.x = c.x; c01.y = c.y;
        c23.x = c.z; c23.y = c.w;
        f32x2 t = q01 * c01;
        t += q23 * c23;
        return t.x + t.y;
    };

    float m;
    {
        float p = dotc(qf);
        p = dpp_reduce<16>(p);
        const float pb = __shfl(p, gtop, 64);
        m = (pb != 0.0f) ? pb : -INFINITY;
    }
    float mt = m - 100.0f;

    // Cauchy-Schwarz ballot-compaction
    int kk = 0;
    {
        const bool keepall = (m == -INFINITY);
        const float sq = keepall ? 0.0f : sqrtf(m) * 1.001f;
        for (int j0 = 0; j0 < kraw; j0 += 64) {
            const int j = j0 + lane;
            bool keep = false;
            int id = 0;
            if (j < kraw) {
                id = myidx[j];
                keep = keepall || (nb[id] * sq * 1.01f + 4.0f > mt);
            }
            const unsigned long long mk = __ballot(keep);
            if (keep) s_off[wave][kk + __popcll(mk & below)] = id * RB;
            kk += __popcll(mk);
        }
        for (int z = kk + lane; z < kk + 48; z += 64) s_off[wave][z] = 0;
    }

    float s = 0.0f;
    float4 acc = {0.0f, 0.0f, 0.0f, 0.0f};

    auto process = [&](const float4 cur) {
        float p = dotc(cur);
        p = dpp_reduce<16>(p);
        if (__builtin_expect((__ballot(p > mt) & 0x8000800080008000ULL) != 0ULL, 0)) {
            const float pb = __shfl(p, gtop, 64);
            const bool valid = (pb != 0.0f);
            const float pm   = valid ? pb : m;
            const float newm = fmaxf(m, pm);
            const float f = (m == newm) ? 1.0f : __expf(m - newm);
            const float e = valid ? __expf(pb - newm) : 0.0f;
            s = s * f + e;
            acc.x = acc.x * f + e * cur.x;
            acc.y = acc.y * f + e * cur.y;
            acc.z = acc.z * f + e * cur.z;
            acc.w = acc.w * f + e * cur.w;
            m = newm;
            mt = m - 100.0f;
        }
    };

    // depth-2 data + depth-4 offset pipeline over the COMPACTED list
    {
        float4 r0, r1, r2;
        int oA, oB, oC;
        oA = s_off[wave][grp + 2 * GS];
        oB = s_off[wave][grp + 3 * GS];
        r0 = *(const float4*)(hb + s_off[wave][grp] + lb);
        r1 = *(const float4*)(hb + s_off[wave][grp + GS] + lb);
        int j = grp;
        while (j < kk) {
            oC = s_off[wave][j + 4 * GS];
            r2 = *(const float4*)(hb + oA + lb);
            process(r0);
            j += GS; if (j >= kk) break;
            oA = s_off[wave][j + 4 * GS];
            r0 = *(const float4*)(hb + oB + lb);
            process(r1);
            j += GS; if (j >= kk) break;
            oB = s_off[wave][j + 4 * GS];
            r1 = *(const float4*)(hb + oC + lb);
            process(r2);
            j += GS;
        }
    }

    // merge the 4 subgroup states (xor 16, 32)
#pragma unroll
    for (int mask = 16; mask <= 32; mask <<= 1) {
        const float m2 = __shfl_xor(m, mask, 64);
        const float s2 = __shfl_xor(s, mask, 64);
        float4 a2;
        a2.x = __shfl_xor(acc.x, mask, 64);
        a2.y = __shfl_xor(acc.y, mask, 64);
        a2.z = __shfl_xor(acc.z, mask, 64);
        a2.w = __shfl_xor(acc.w, mask, 64);
        const float mm = fmaxf(m, m2);
        const float f1 = (m  == mm) ? 1.0f : __expf(m  - mm);
        const float f2 = (m2 == mm) ? 1.0f : __expf(m2 - mm);
        s = s * f1 + s2 * f2;
        acc.x = acc.x * f1 + a2.x * f2;
        acc.y = acc.y * f1 + a2.y * f2;
        acc.z = acc.z * f1 + a2.z * f2;
        acc.w = acc.w * f1 + a2.w * f2;
        m = mm;
    }

    if (s > 0.0f) {
        if (grp == 0) {
            const float4 bi = ((const float4*)bias)[gl];
            const float inv = 1.0f / s;
            float4 o;
            o.x = acc.x * inv + bi.x;
            o.y = acc.y * inv + bi.y;
            o.z = acc.z * inv + bi.z;
            o.w = acc.w * inv + bi.w;
            ((float4*)out)[((size_t)b * N_ + n) * V + gl] = o;
        }
    } else {
        const float4* hb4 = (const float4*)hb;
        const int sl = lane % V;
        const int rs = lane / V;
        float4 a = {0.0f, 0.0f, 0.0f, 0.0f};
        for (int row = rs; row < N_; row += 4) {
            float4 v = hb4[(size_t)row * V + sl];
            a.x += v.x; a.y += v.y; a.z += v.z; a.w += v.w;
        }
#pragma unroll
        for (int mask = 16; mask <= 32; mask <<= 1) {
            a.x += __shfl_xor(a.x, mask, 64);
            a.y += __shfl_xor(a.y, mask, 64);
            a.z += __shfl_xor(a.z, mask, 64);
            a.w += __shfl_xor(a.w, mask, 64);
        }
        if (lane < V) {
            constexpr float invN = 1.0f / (float)N_;
            const float4 bi = ((const float4*)bias)[sl];
            float4 o;
            o.x = a.x * invN + bi.x;
            o.y = a.y * invN + bi.y;
            o.z = a.z * invN + bi.z;
            o.w = a.w * invN + bi.w;
            ((float4*)out)[((size_t)b * N_ + n) * V + sl] = o;
        }
    }
}

// ---------------------------------------------------------------------------
// Launch
// ---------------------------------------------------------------------------
extern "C" void kernel_launch(void* const* d_in, const int* in_sizes, int n_in,
                              void* d_out, int out_size, void* d_ws, size_t ws_size,
                              hipStream_t stream) {
    (void)in_sizes; (void)n_in; (void)out_size; (void)ws_size;

    const float* flow_x = (const float*)d_in[0];
    const float* graph  = (const float*)d_in[1];
    const float* W1     = (const float*)d_in[2];
    const float* b1     = (const float*)d_in[3];
    const float* W2     = (const float*)d_in[4];
    const float* b2     = (const float*)d_in[5];
    float* out = (float*)d_out;

    char* p = (char*)d_ws;
    auto carve = [&](size_t bytes) -> void* {
        void* r = (void*)p;
        p += (bytes + 255) & ~(size_t)255;
        return r;
    };
    int*   nbr_cnt = (int*)carve((size_t)N_ * sizeof(int));
    int*   nbr_idx = (int*)carve((size_t)N_ * MAXDEG * sizeof(int));
    float* h1      = (float*)carve((size_t)B_ * N_ * DHID * sizeof(float));
    void*  h1b     = carve((size_t)B_ * N_ * DHID * 2);   // bf16 copy
    float* x2      = (float*)carve((size_t)B_ * N_ * DHID * sizeof(float));
    float* h2      = (float*)carve((size_t)B_ * N_ * DOUT2 * sizeof(float));
    float* nrm1    = (float*)carve((size_t)B_ * N_ * sizeof(float));
    float* nrm2    = (float*)carve((size_t)B_ * N_ * sizeof(float));

    // 1. adjacency -> neighbor lists
    k_build_csr<<<N_ / 4, 256, 0, stream>>>(graph, nbr_cnt, nbr_idx);

    // 2. layer 1 linear: fp32 h1 + bf16 h1b + row norms (LDS epilogue)
    k_linear1<<<(B_ * N_) / 32, 256, 0, stream>>>(flow_x, W1, h1, h1b, nrm1);

    // 3. layer 1 attention: CS-compacted bf16 gather/score, fp32 acc -> x2
    k_attn1<<<N_ * B_ / 4, 256, 0, stream>>>(h1b, h1, nrm1, nbr_cnt, nbr_idx, b1, x2);

    // 4. layer 2 linear (fp32) + row norms (LDS epilogue)
    k_linear<DHID, DOUT2><<<(B_ * N_) / 32, 256, 0, stream>>>(x2, W2, h2, nrm2);

    // 5. layer 2 attention (fp32, GS=4, CS-compacted) -> d_out
    k_attn2<<<N_ * B_ / 4, 256, 0, stream>>>(h2, nrm2, nbr_cnt, nbr_idx, b2, out);
}